// Round 2
// baseline (180.520 us; speedup 1.0000x reference)
//
#include <hip/hip_runtime.h>
#include <math.h>

#define N 8
#define C 256
#define L 512
#define K 100
#define NL (N * L)
#define TEMP_INV 2.0f          // sims are multiplied by 2 (1/TEMP) before LSE
#define EPSN 1e-8f
#define NEG_BIG -1e30f         // finite stand-in for -inf (avoids inf-inf NaN)

// ws layout (floats): zt[NL*C] | ct[NL*C] | zinv[NL] | cinv[NL]

// K1: one 64x64 tile per block (512 blocks). (N,C,L)->(NL,C) transpose for z
// and c (dropping c's start token). Also zeroes the output accumulator.
__global__ __launch_bounds__(256) void transpose_kernel(
    const float* __restrict__ z, const float* __restrict__ c,
    float* __restrict__ zt, float* __restrict__ ct, float* __restrict__ out)
{
    if (blockIdx.x == 0 && threadIdx.x == 0) out[0] = 0.f;

    __shared__ float lds[64 * 65];          // +1 pad: conflict-free both phases
    const int tiles_per_src = N * (C / 64) * (L / 64);   // 8*4*8 = 256
    const int b    = blockIdx.x;
    const int is_c = b >= tiles_per_src;
    const int bb   = is_c ? b - tiles_per_src : b;
    const int n    = bb >> 5;               // 32 tiles per n (4 c-tiles x 8 l-tiles)
    const int rem  = bb & 31;
    const int c0   = (rem >> 3) << 6;
    const int l0   = (rem & 7) << 6;
    const int ld   = is_c ? (L + 1) : L;
    const float* src = is_c ? (c + (size_t)n * C * (L + 1) + 1)
                            : (z + (size_t)n * C * L);
    float* dst = (is_c ? ct : zt) + (size_t)n * L * C;

    const int t = threadIdx.x, tx = t & 63, ty = t >> 6;
    #pragma unroll
    for (int i = 0; i < 16; ++i) {
        int cl = i * 4 + ty;
        lds[cl * 65 + tx] = src[(size_t)(c0 + cl) * ld + l0 + tx];   // coalesced in tx (=l)
    }
    __syncthreads();
    #pragma unroll
    for (int i = 0; i < 16; ++i) {
        int ll = i * 4 + ty;
        dst[(size_t)(l0 + ll) * C + c0 + tx] = lds[tx * 65 + ll];    // coalesced in tx (=c)
    }
}

// K2: one wave per row (8192 rows: zt then ct) -> inverse norms.
__global__ __launch_bounds__(256) void norm_kernel(
    const float* __restrict__ zt, const float* __restrict__ ct,
    float* __restrict__ zinv, float* __restrict__ cinv)
{
    const int w = threadIdx.x >> 6, lane = threadIdx.x & 63;
    const int r = blockIdx.x * 4 + w;                 // 0..8191
    const float* src = (r < NL) ? zt : ct;
    float* dstv      = (r < NL) ? zinv : cinv;
    const int row    = (r < NL) ? r : r - NL;
    float4 v = *(const float4*)(src + (size_t)row * C + lane * 4);
    float d = v.x * v.x + v.y * v.y + v.z * v.z + v.w * v.w;
    #pragma unroll
    for (int m = 1; m < 64; m <<= 1) d += __shfl_xor(d, m, 64);
    if (lane == 0) dstv[row] = 1.f / fmaxf(sqrtf(d), EPSN);
}

// K3: wave per row, lane per 2 targets (128 padded: 0=positive, 1..100=negs).
// Context row read via wave-uniform scalar loads; no cross-lane ops in loop.
__global__ __launch_bounds__(256) void logits_kernel(
    const float* __restrict__ zt, const float* __restrict__ ct,
    const float* __restrict__ zinv, const float* __restrict__ cinv,
    const int* __restrict__ neg, float* __restrict__ out)
{
    const int w = threadIdx.x >> 6, lane = threadIdx.x & 63;
    const int row = __builtin_amdgcn_readfirstlane(blockIdx.x * 4 + w);

    const int t0 = lane;                 // 0..63 (0 = positive)
    const int t1 = lane + 64;            // 64..127, real iff <= 100
    const bool real1 = (t1 <= K);
    const int idx0 = (t0 == 0) ? row : neg[(size_t)row * K + t0 - 1];
    const int idx1 = real1 ? neg[(size_t)row * K + t1 - 1] : idx0;

    const float* __restrict__ p0 = zt + (size_t)idx0 * C;
    const float* __restrict__ p1 = zt + (size_t)idx1 * C;
    const float* __restrict__ cr = ct + (size_t)row * C;   // uniform -> s_load

    float ax = 0, ay = 0, az = 0, aw = 0;
    float bx = 0, by = 0, bz = 0, bw = 0;
    #pragma unroll 8
    for (int j = 0; j < 64; ++j) {
        const float4 n0 = *(const float4*)(p0 + j * 4);
        const float4 n1 = *(const float4*)(p1 + j * 4);
        const float c0 = cr[j * 4 + 0], c1 = cr[j * 4 + 1];
        const float c2 = cr[j * 4 + 2], c3 = cr[j * 4 + 3];
        ax = fmaf(c0, n0.x, ax); ay = fmaf(c1, n0.y, ay);
        az = fmaf(c2, n0.z, az); aw = fmaf(c3, n0.w, aw);
        bx = fmaf(c0, n1.x, bx); by = fmaf(c1, n1.y, by);
        bz = fmaf(c2, n1.z, bz); bw = fmaf(c3, n1.w, bw);
    }
    const float d0 = (ax + ay) + (az + aw);
    const float d1 = (bx + by) + (bz + bw);

    const float ci = cinv[row];
    float sim0 = d0 * ci * zinv[idx0] * TEMP_INV;
    float sim1 = real1 ? d1 * ci * zinv[idx1] * TEMP_INV : NEG_BIG;

    // mask negatives exactly equal to the context vector (rare path; sims are
    // x2 here so cos ~ 1 maps to ~2)
    if (t0 > 0 && sim0 > 1.99998f) {
        bool eq = true;
        for (int j = 0; j < C; ++j) eq = eq && (cr[j] == p0[j]);
        if (eq) sim0 = NEG_BIG;
    }
    if (real1 && sim1 > 1.99998f) {
        bool eq = true;
        for (int j = 0; j < C; ++j) eq = eq && (cr[j] == p1[j]);
        if (eq) sim1 = NEG_BIG;
    }

    const float pos = __shfl(sim0, 0, 64);   // lane 0's target 0 = positive

    // per-lane partial LSE over its 2 targets, then one butterfly per row.
    // NEG_BIG entries contribute exp(NEG_BIG - M) = 0 once any finite max
    // dominates (lane 0 is always finite), so no NaN guards needed.
    float mx = fmaxf(sim0, sim1);
    float s  = __expf(sim0 - mx) + __expf(sim1 - mx);
    #pragma unroll
    for (int m = 1; m < 64; m <<= 1) {
        const float omx = __shfl_xor(mx, m, 64);
        const float os  = __shfl_xor(s,  m, 64);
        const float M   = fmaxf(mx, omx);
        s  = s * __expf(mx - M) + os * __expf(omx - M);
        mx = M;
    }
    if (lane == 0) atomicAdd(out, (mx + __logf(s) - pos) * (1.0f / NL));
}

extern "C" void kernel_launch(void* const* d_in, const int* in_sizes, int n_in,
                              void* d_out, int out_size, void* d_ws, size_t ws_size,
                              hipStream_t stream) {
    const float* z = (const float*)d_in[0];
    const float* c = (const float*)d_in[1];
    const int* neg = (const int*)d_in[2];
    float* out = (float*)d_out;

    float* zt   = (float*)d_ws;
    float* ct   = zt + (size_t)NL * C;
    float* zinv = ct + (size_t)NL * C;
    float* cinv = zinv + NL;

    transpose_kernel<<<512, 256, 0, stream>>>(z, c, zt, ct, out);
    norm_kernel<<<2 * NL / 4, 256, 0, stream>>>(zt, ct, zinv, cinv);
    logits_kernel<<<NL / 4, 256, 0, stream>>>(zt, ct, zinv, cinv, neg, out);
}

// Round 3
// 139.241 us; speedup vs baseline: 1.2965x; 1.2965x over previous
//
#include <hip/hip_runtime.h>
#include <math.h>

#define N 8
#define C 256
#define L 512
#define K 100
#define NL (N * L)
#define EPSN 1e-8f

// ws layout (floats): zt[NL*C] | ct[NL*C] | zinv[NL] | cinv[NL]

// K1: transpose (N,C,L)->(NL,C) for z and c (drop start token) + fused
// inverse norms + zero the loss accumulator. Block = 16 l's x 256 c's.
__global__ __launch_bounds__(256) void prep_kernel(
    const float* __restrict__ z, const float* __restrict__ c,
    float* __restrict__ zt, float* __restrict__ ct,
    float* __restrict__ zinv, float* __restrict__ cinv,
    float* __restrict__ out)
{
    if (blockIdx.x == 0 && threadIdx.x == 0) out[0] = 0.f;

    __shared__ float tile[256 * 17];   // [c][l] with +1 pad
    __shared__ float red[256];

    const int b    = blockIdx.x;
    const int is_c = b >= 256;
    const int bb   = is_c ? b - 256 : b;
    const int n    = bb >> 5;            // 32 blocks per n
    const int l0   = (bb & 31) << 4;     // 16 l's per block
    const int ld   = is_c ? (L + 1) : L;
    const float* src = (is_c ? c : z) + (size_t)n * C * ld + (is_c ? 1 : 0) + l0;
    float* dst = (is_c ? ct : zt) + (size_t)(n * L + l0) * C;
    float* inv = (is_c ? cinv : zinv) + n * L + l0;

    const int t   = threadIdx.x;
    const int lcl = t & 15;              // local l
    const int cc0 = t >> 4;              // c base (16 c's per thread)

    float ss = 0.f;
    #pragma unroll
    for (int i = 0; i < 16; ++i) {
        const int cidx = i * 16 + cc0;
        const float v = src[(size_t)cidx * ld + lcl];
        tile[cidx * 17 + lcl] = v;
        ss += v * v;
    }
    red[t] = ss;
    __syncthreads();
    #pragma unroll
    for (int j = 0; j < 16; ++j)
        dst[(size_t)j * C + t] = tile[t * 17 + j];      // coalesced 1KB stores
    if (t < 16) {
        float tot = 0.f;
        #pragma unroll
        for (int j = 0; j < 16; ++j) tot += red[j * 16 + t];
        inv[t] = 1.f / fmaxf(sqrtf(tot), EPSN);
    }
}

// K2: one wave per row. 128 padded targets (0=positive, 1..100=negs) in 4
// batches of 32. Phase 1: coalesced 1KB row gather, per-lane float4 partial,
// one ds_write_b32 per negative (XOR-swizzled, conflict-free). Phase 2:
// lane n / n+32 read neg n's 64 partials as 8 ds_read_b128 each
// (conflict-free), one shfl to join halves. Fixed-max LSE (logits <= 2).
__global__ __launch_bounds__(256) void logits_kernel(
    const float* __restrict__ zt, const float* __restrict__ ct,
    const float* __restrict__ zinv, const float* __restrict__ cinv,
    const int* __restrict__ neg, float* __restrict__ out)
{
    __shared__ float parts[4][32 * 64];  // 8 KB per wave

    const int w    = threadIdx.x >> 6;
    const int lane = threadIdx.x & 63;
    const int row  = __builtin_amdgcn_readfirstlane(blockIdx.x * 4 + w);
    const int* __restrict__ negp = neg + (size_t)row * K;
    float* __restrict__ buf = &parts[w][0];

    const float4 cf = *(const float4*)(ct + (size_t)row * C + lane * 4);
    const float  ci = cinv[row];
    const float* __restrict__ cr = ct + (size_t)row * C;

    const int u = lane >> 2, sub = lane & 3;

    float s_acc = 0.f;
    float pos   = 0.f;

    for (int b = 0; b < 4; ++b) {
        // ---- phase 1: 32 coalesced gathered dots -> LDS partials ----
        #pragma unroll 8
        for (int r = 0; r < 32; ++r) {
            const int t = b * 32 + r;
            const int idx = (t >= 1 && t <= K)
                ? __builtin_amdgcn_readfirstlane(negp[t - 1]) : row;
            const float4 zr = *(const float4*)(zt + (size_t)idx * C + (lane << 2));
            const float p = fmaf(cf.x, zr.x, fmaf(cf.y, zr.y,
                             fmaf(cf.z, zr.z, cf.w * zr.w)));
            buf[(r << 6) + (((u ^ (r & 15)) << 2) | sub)] = p;
        }
        // ---- phase 2: redistribute, finish dots, accumulate exp ----
        const int nn = lane & 31, half = lane >> 5;
        float4 a4 = {0.f, 0.f, 0.f, 0.f};
        #pragma unroll
        for (int j = 0; j < 8; ++j) {
            const int uu = half * 8 + j;
            const float4 v = *(const float4*)(buf + (nn << 6) + ((uu ^ (nn & 15)) << 2));
            a4.x += v.x; a4.y += v.y; a4.z += v.z; a4.w += v.w;
        }
        const float dh = (a4.x + a4.y) + (a4.z + a4.w);
        const float dfull = dh + __shfl_xor(dh, 32, 64);

        const int t = b * 32 + nn;
        const int idxv = (t >= 1 && t <= K) ? negp[t - 1] : row;
        const float sim2 = dfull * ci * zinv[idxv] * 2.0f;   // logit = 2*cos
        if (b == 0 && lane == 0) pos = sim2;

        bool use = (half == 0) && (t <= K);
        if (use && t >= 1 && sim2 > 1.9999f) {     // exact-equal mask (rare)
            const float* zp = zt + (size_t)idxv * C;
            bool eq = true;
            for (int j = 0; j < C; ++j) eq = eq && (cr[j] == zp[j]);
            if (eq) use = false;
        }
        if (use) s_acc += __expf(sim2 - 2.0f);
    }

    #pragma unroll
    for (int m = 1; m < 64; m <<= 1) s_acc += __shfl_xor(s_acc, m, 64);
    if (lane == 0)
        atomicAdd(out, (2.0f + __logf(s_acc) - pos) * (1.0f / NL));
}

extern "C" void kernel_launch(void* const* d_in, const int* in_sizes, int n_in,
                              void* d_out, int out_size, void* d_ws, size_t ws_size,
                              hipStream_t stream) {
    const float* z = (const float*)d_in[0];
    const float* c = (const float*)d_in[1];
    const int* neg = (const int*)d_in[2];
    float* out = (float*)d_out;

    float* zt   = (float*)d_ws;
    float* ct   = zt + (size_t)NL * C;
    float* zinv = ct + (size_t)NL * C;
    float* cinv = zinv + NL;

    prep_kernel<<<512, 256, 0, stream>>>(z, c, zt, ct, zinv, cinv, out);
    logits_kernel<<<NL / 4, 256, 0, stream>>>(zt, ct, zinv, cinv, neg, out);
}

// Round 4
// 97.174 us; speedup vs baseline: 1.8577x; 1.4329x over previous
//
#include <hip/hip_runtime.h>
#include <math.h>

#define N 8
#define C 256
#define L 512
#define K 100
#define NL (N * L)
#define EPSN 1e-8f

// ws layout (floats): zt[NL*C] | ct[NL*C] | zinv[NL] | cinv[NL] | partials[1024]

// K1: transpose (N,C,L)->(NL,C) for z and c (drop start token) + fused
// inverse norms. Block = 16 l's x 256 c's.
__global__ __launch_bounds__(256) void prep_kernel(
    const float* __restrict__ z, const float* __restrict__ c,
    float* __restrict__ zt, float* __restrict__ ct,
    float* __restrict__ zinv, float* __restrict__ cinv)
{
    __shared__ float tile[256 * 17];   // [c][l] with +1 pad
    __shared__ float red[256];

    const int b    = blockIdx.x;
    const int is_c = b >= 256;
    const int bb   = is_c ? b - 256 : b;
    const int n    = bb >> 5;            // 32 blocks per n
    const int l0   = (bb & 31) << 4;     // 16 l's per block
    const int ld   = is_c ? (L + 1) : L;
    const float* src = (is_c ? c : z) + (size_t)n * C * ld + (is_c ? 1 : 0) + l0;
    float* dst = (is_c ? ct : zt) + (size_t)(n * L + l0) * C;
    float* inv = (is_c ? cinv : zinv) + n * L + l0;

    const int t   = threadIdx.x;
    const int lcl = t & 15;              // local l
    const int cc0 = t >> 4;              // c base

    float ss = 0.f;
    #pragma unroll
    for (int i = 0; i < 16; ++i) {
        const int cidx = i * 16 + cc0;
        const float v = src[(size_t)cidx * ld + lcl];
        tile[cidx * 17 + lcl] = v;
        ss += v * v;
    }
    red[t] = ss;
    __syncthreads();
    #pragma unroll
    for (int j = 0; j < 16; ++j)
        dst[(size_t)j * C + t] = tile[t * 17 + j];      // coalesced 1KB stores
    if (t < 16) {
        float tot = 0.f;
        #pragma unroll
        for (int j = 0; j < 16; ++j) tot += red[j * 16 + t];
        inv[t] = 1.f / fmaxf(sqrtf(tot), EPSN);
    }
}

// K2: one wave per row. 128 padded targets (0=positive, 1..100=negs) in 4
// batches of 32. Phase 1: coalesced 1KB row gather (16 loads in flight),
// per-lane float4 partial, XOR-swizzled ds_write_b32 (conflict-free).
// Phase 2: conflict-free ds_read_b128 redistribute + 1 shfl. Fixed-max LSE
// (logits = 2*cos <= 2). NO global atomic: block partial -> ws.
__global__ __launch_bounds__(256) void logits_kernel(
    const float* __restrict__ zt, const float* __restrict__ ct,
    const float* __restrict__ zinv, const float* __restrict__ cinv,
    const int* __restrict__ neg, float* __restrict__ partials)
{
    __shared__ float parts[4][32 * 64];  // 8 KB per wave
    __shared__ float wterm[4];

    const int w    = threadIdx.x >> 6;
    const int lane = threadIdx.x & 63;
    const int row  = __builtin_amdgcn_readfirstlane(blockIdx.x * 4 + w);
    const int* __restrict__ negp = neg + (size_t)row * K;
    float* __restrict__ buf = &parts[w][0];

    const float4 cf = *(const float4*)(ct + (size_t)row * C + lane * 4);
    const float  ci = cinv[row];
    const float* __restrict__ cr = ct + (size_t)row * C;

    const int u = lane >> 2, sub = lane & 3;

    float s_acc = 0.f;
    float pos   = 0.f;

    for (int b = 0; b < 4; ++b) {
        // ---- phase 1: 32 coalesced gathered dots -> LDS partials ----
        #pragma unroll 16
        for (int r = 0; r < 32; ++r) {
            const int t = b * 32 + r;
            const int idx = (t >= 1 && t <= K)
                ? __builtin_amdgcn_readfirstlane(negp[t - 1]) : row;
            const float4 zr = *(const float4*)(zt + (size_t)idx * C + (lane << 2));
            const float p = fmaf(cf.x, zr.x, fmaf(cf.y, zr.y,
                             fmaf(cf.z, zr.z, cf.w * zr.w)));
            buf[(r << 6) + (((u ^ (r & 15)) << 2) | sub)] = p;
        }
        // ---- phase 2: redistribute, finish dots, accumulate exp ----
        const int nn = lane & 31, half = lane >> 5;
        float4 a4 = {0.f, 0.f, 0.f, 0.f};
        #pragma unroll
        for (int j = 0; j < 8; ++j) {
            const int uu = half * 8 + j;
            const float4 v = *(const float4*)(buf + (nn << 6) + ((uu ^ (nn & 15)) << 2));
            a4.x += v.x; a4.y += v.y; a4.z += v.z; a4.w += v.w;
        }
        const float dh = (a4.x + a4.y) + (a4.z + a4.w);
        const float dfull = dh + __shfl_xor(dh, 32, 64);

        const int t = b * 32 + nn;
        const int idxv = (t >= 1 && t <= K) ? negp[t - 1] : row;
        const float sim2 = dfull * ci * zinv[idxv] * 2.0f;   // logit = 2*cos
        if (b == 0 && lane == 0) pos = sim2;

        bool use = (half == 0) && (t <= K);
        if (use && t >= 1 && sim2 > 1.9999f) {     // exact-equal mask (rare)
            const float* zp = zt + (size_t)idxv * C;
            bool eq = true;
            for (int j = 0; j < C; ++j) eq = eq && (cr[j] == zp[j]);
            if (eq) use = false;
        }
        if (use) s_acc += __expf(sim2 - 2.0f);
    }

    #pragma unroll
    for (int m = 1; m < 64; m <<= 1) s_acc += __shfl_xor(s_acc, m, 64);
    if (lane == 0) wterm[w] = 2.0f + __logf(s_acc) - pos;   // row loss term
    __syncthreads();
    if (threadIdx.x == 0)
        partials[blockIdx.x] = wterm[0] + wterm[1] + wterm[2] + wterm[3];
}

// K3: reduce 1024 block partials -> mean loss.
__global__ __launch_bounds__(256) void reduce_kernel(
    const float* __restrict__ partials, float* __restrict__ out)
{
    __shared__ float red[4];
    const int t = threadIdx.x;
    float s = partials[t] + partials[t + 256] + partials[t + 512] + partials[t + 768];
    #pragma unroll
    for (int m = 1; m < 64; m <<= 1) s += __shfl_xor(s, m, 64);
    if ((t & 63) == 0) red[t >> 6] = s;
    __syncthreads();
    if (t == 0) out[0] = (red[0] + red[1] + red[2] + red[3]) * (1.0f / NL);
}

extern "C" void kernel_launch(void* const* d_in, const int* in_sizes, int n_in,
                              void* d_out, int out_size, void* d_ws, size_t ws_size,
                              hipStream_t stream) {
    const float* z = (const float*)d_in[0];
    const float* c = (const float*)d_in[1];
    const int* neg = (const int*)d_in[2];
    float* out = (float*)d_out;

    float* zt   = (float*)d_ws;
    float* ct   = zt + (size_t)NL * C;
    float* zinv = ct + (size_t)NL * C;
    float* cinv = zinv + NL;
    float* partials = cinv + NL;

    prep_kernel<<<512, 256, 0, stream>>>(z, c, zt, ct, zinv, cinv);
    logits_kernel<<<NL / 4, 256, 0, stream>>>(zt, ct, zinv, cinv, neg, partials);
    reduce_kernel<<<1, 256, 0, stream>>>(partials, out);
}